// Round 10
// baseline (408.405 us; speedup 1.0000x reference)
//
#include <hip/hip_runtime.h>
#include <hip/hip_bf16.h>
#include <math.h>

#define EPSF 1e-8f
#define LR   1e-3f

#define HH 512
#define KK 64
#define SS 8          // samples per block (4 waves x 2 sample-groups)
#define PbStrD 52     // Pb row stride in DWORDS: 48 data (s-pair x z x m) + 4 pad
#define GbStr 136     // Gb col stride (ush): 128 K + 8 pad
#define SLICE 4096    // per-wave slice (ush) = 8192 B
#define OutStr 193    // pool fp32 out-stage stride (floats) per sample

typedef short    bf16x8 __attribute__((ext_vector_type(8)));
typedef _Float16 f16x8  __attribute__((ext_vector_type(8)));
typedef float    f32x4  __attribute__((ext_vector_type(4)));
typedef unsigned int u32x4 __attribute__((ext_vector_type(4)));

__device__ __forceinline__ unsigned short f2bf(float x) {
  unsigned int u = __float_as_uint(x);
  return (unsigned short)((u + 0x7fffu + ((u >> 16) & 1u)) >> 16);
}
__device__ __forceinline__ float bfhi(float x) {
  return __uint_as_float(((unsigned int)f2bf(x)) << 16);
}
__device__ __forceinline__ unsigned short f2h(float x) {
  _Float16 h = (_Float16)x;
  return *(unsigned short*)&h;
}
__device__ __forceinline__ unsigned int pkbf2(float a, float b) {
  union { __hip_bfloat162 h; unsigned int u; } cv;
  cv.h = __float22bfloat162_rn(make_float2(a, b));
  return cv.u;
}
// select f16 half of dword by shift (sh = 0 or 16), convert to f32
__device__ __forceinline__ float hsel(unsigned int w, unsigned int sh) {
  unsigned short b = (unsigned short)(w >> sh);
  _Float16 h; __builtin_memcpy(&h, &b, 2); return (float)h;
}

// elementwise gradient, kappa^2 formulation (no nc sqrt, fused rcps)
__device__ __forceinline__ void elemf(
    float P0, float P1, float P2, float V0, float V1, float V2,
    float A0, float A1, float A2, float J0, float J1, float J2,
    float aa, float bb, float r0, float r1, float r2,
    float l1, float l2, float l3,
    float& o0, float& o1, float& o2, float& o3, float& o4, float& o5,
    float& o6, float& o7, float& o8, float& o9, float& o10, float& o11) {
  const float LNLO = -9.210340371976182f;   // ln(1e-4)
  const float LNHI =  9.210340371976182f;   // ln(1e4)
  float v2 = V0*V0 + V1*V1 + V2*V2;
  float v  = __builtin_amdgcn_sqrtf(v2);
  float ve = v + EPSF;
  float cx0 = V1*A2 - V2*A1;
  float cx1 = V2*A0 - V0*A2;
  float cx2 = V0*A1 - V1*A0;
  float nc2 = cx0*cx0 + cx1*cx1 + cx2*cx2;
  float ve2 = ve*ve;
  float denom = ve2*ve + EPSF;
  float invd  = __builtin_amdgcn_rcpf(denom);
  float kap2  = nc2 * invd * invd;          // kappa^2
  float lnk   = 0.5f * __logf(kap2);        // ln(kappa)
  float lnkc  = fminf(fmaxf(lnk, LNLO), LNHI);
  float lpr = bb * lnkc;
  float lp  = fminf(fmaxf(lpr, -10.f), 10.f);
  float tr  = aa * __expf(lp);
  float tt  = fminf(fmaxf(tr, 1e-6f), 1e6f);
  float s2  = 2.f*l2*(v - tt);
  float gtr  = (tr > 1e-6f && tr < 1e6f) ? -s2 : 0.f;
  float glpr = (lpr > -10.f && lpr < 10.f) ? gtr*tr : 0.f;
  bool  kin  = (lnk > LNLO) && (lnk < LNHI);
  float gb   = glpr * bb;
  float tcs  = gb * __builtin_amdgcn_rcpf(nc2);
  float gcs2 = kin ? tcs : 0.f;
  float gden = kin ? (-gb * invd) : 0.f;
  float gve  = 3.f * ve2 * gden;
  float gv   = s2 + gve;
  float giv  = gv * __builtin_amdgcn_rcpf(v);
  float gc0 = gcs2*cx0, gc1 = gcs2*cx1, gc2 = gcs2*cx2;
  o0  = 2.f*l1*(P0 - r0);
  o1  = 2.f*l1*(P1 - r1);
  o2  = 2.f*l1*(P2 - r2);
  o3  = fmaf(giv, V0, A1*gc2 - A2*gc1);
  o4  = fmaf(giv, V1, A2*gc0 - A0*gc2);
  o5  = fmaf(giv, V2, A0*gc1 - A1*gc0);
  o6  = gc1*V2 - gc2*V1;
  o7  = gc2*V0 - gc0*V2;
  o8  = gc0*V1 - gc1*V0;
  o9  = 2.f*l3*J0;
  o10 = 2.f*l3*J1;
  o11 = 2.f*l3*J2;
}

// ws layout (ushort units) — UNCHANGED:
//  AFb @ 0      (131072): bwd A-frags, single bf16
//  AFf @ 131072 (131072): fwd A-frags fp16
//  AFp @ 262144 (65536): C0 A-frags bf16 hi/lo (Bp)
__global__ void prep_kernel(const float* __restrict__ B,
                            const float* __restrict__ Bd,
                            const float* __restrict__ Bdd,
                            const float* __restrict__ Bddd,
                            const float* __restrict__ Bp,
                            unsigned short* __restrict__ ws) {
  int tid = blockIdx.x * 256 + threadIdx.x;   // 640 * 256 = 163840
  const float* Ms[4] = {B, Bd, Bdd, Bddd};
  unsigned short bits[2];
  if (tid < 65536) {
    #pragma unroll
    for (int t = 0; t < 2; ++t) {
      unsigned int id = 2u * tid + t;
      int j = id & 7, lane = (id >> 3) & 63;
      int mt = (id >> 9) & 3, ks2 = (id >> 11) & 3;
      int qtr = (id >> 13) & 3, chunk = (id >> 15) & 3;
      int khat = mt * 16 + (lane & 15);
      int kq = ((lane >> 4) << 3) + j;
      int h = chunk * 128 + qtr * 32 + kq;
      bits[t] = f2bf(Ms[ks2][h * 64 + khat]);
    }
    ((unsigned int*)ws)[tid] = ((unsigned int)bits[1] << 16) | bits[0];
  } else if (tid < 131072) {
    int base = tid - 65536;
    #pragma unroll
    for (int t = 0; t < 2; ++t) {
      unsigned int id = 2u * base + t;
      int j = id & 7, lane = (id >> 3) & 63, kap = (id >> 9) & 1;
      int ht = (id >> 10) & 31, z = (id >> 15) & 3;
      int h = ht * 16 + (lane & 15);
      int kk = kap * 32 + ((lane >> 4) << 3) + j;
      bits[t] = f2h(Ms[z][h * 64 + kk]);
    }
    ((unsigned int*)(ws + 131072))[base] = ((unsigned int)bits[1] << 16) | bits[0];
  } else {
    int base = tid - 131072;
    #pragma unroll
    for (int t = 0; t < 2; ++t) {
      unsigned int id = 2u * base + t;
      int j = id & 7, lane = (id >> 3) & 63, hilo = (id >> 9) & 1;
      int mt = (id >> 10) & 3, ks = (id >> 12) & 15;
      int khat = mt * 16 + (lane & 15);
      int Kl = ks * 32 + ((lane >> 4) << 3) + j;
      float val = Bp[khat * 512 + Kl];
      float hi = bfhi(val);
      bits[t] = hilo ? f2bf(val - hi) : f2bf(hi);
    }
    ((unsigned int*)(ws + 262144))[base] = ((unsigned int)bits[1] << 16) | bits[0];
  }
}

// r7 structure + dword-packed Pb ([h][48] dwords, stride 52): fwd stores 64->32
// insts/q, elem loads 12xb64 -> 12xb128 (both sample-halves share addresses).
__global__ __launch_bounds__(256, 3)
void copt_kernel(const float* __restrict__ R_U,
                 const float* __restrict__ alpha,
                 const float* __restrict__ beta,
                 const float* __restrict__ lambdas,
                 const unsigned short* __restrict__ ws,
                 float* __restrict__ out) {
  __shared__ __align__(16) unsigned short Cbf[2 * 1024];   // 4 KB fp16 C B-frags
  __shared__ __align__(16) unsigned short pool[4 * SLICE]; // 32 KB per-wave Pb/Gb/dump

  const unsigned short* AFb = ws;
  const unsigned short* AFf = ws + 131072;
  const unsigned short* AFp = ws + 262144;

  const int tid  = threadIdx.x;
  const int lane = tid & 63;
  const int wid  = tid >> 6;
  const int quad = lane >> 4;
  const int c    = lane & 15;

  const float l1 = lambdas[0], l2 = lambdas[1], l3 = lambdas[2];
  const int bg = blockIdx.x * SS;

  ((float4*)Cbf)[tid] = make_float4(0.f, 0.f, 0.f, 0.f);  // cols 12..15 stay 0

  // ---- stage r -> pool (bf16): [col = sg2*12 + 3*wid + m][h], stride 520 ----
  #pragma unroll
  for (int sg2 = 0; sg2 < 2; ++sg2) {
    const int colb = sg2 * 12 + 3 * wid;
    const float4* rp = (const float4*)(R_U + (size_t)(bg + wid + sg2 * 4) * (HH * 3));
    #pragma unroll
    for (int i = 0; i < 6; ++i) {
      float4 v = rp[i * 64 + lane];
      int e = (i * 64 + lane) * 4;
      const float* pv = &v.x;
      #pragma unroll
      for (int d = 0; d < 4; ++d) {
        int ee = e + d, h = ee / 3, m = ee - 3 * h;
        pool[(colb + m) * 520 + h] = f2bf(pv[d]);
      }
    }
  }
  __syncthreads();

  f32x4 Creg0 = {0.f, 0.f, 0.f, 0.f};
  f32x4 Creg1 = {0.f, 0.f, 0.f, 0.f};
  const int sl = (c * 86) >> 8, fm = c - 3 * sl;
  const int kr = wid * 16 + quad * 4;

  // ---- C0 = Bp @ r via MFMA ----
  {
    const unsigned short* gb0 = &pool[c * 520 + quad * 8];
    const unsigned short* gb1 = &pool[(12 + c) * 520 + quad * 8];
    __builtin_amdgcn_s_setprio(1);
    #pragma unroll 4
    for (int ks = 0; ks < 16; ++ks) {
      const unsigned short* pA = AFp + (size_t)((ks * 4 + wid) * 2) * 512 + lane * 8;
      bf16x8 ah = *(const bf16x8*)pA;
      bf16x8 al = *(const bf16x8*)(pA + 512);
      bf16x8 g0 = *(const bf16x8*)(gb0 + ks * 32);
      bf16x8 g1 = *(const bf16x8*)(gb1 + ks * 32);
      Creg0 = __builtin_amdgcn_mfma_f32_16x16x32_bf16(ah, g0, Creg0, 0, 0, 0);
      Creg0 = __builtin_amdgcn_mfma_f32_16x16x32_bf16(al, g0, Creg0, 0, 0, 0);
      Creg1 = __builtin_amdgcn_mfma_f32_16x16x32_bf16(ah, g1, Creg1, 0, 0, 0);
      Creg1 = __builtin_amdgcn_mfma_f32_16x16x32_bf16(al, g1, Creg1, 0, 0, 0);
    }
    __builtin_amdgcn_s_setprio(0);
    if (c < 12) {
      #pragma unroll
      for (int r = 0; r < 4; ++r) {
        int k = kr + r;
        Cbf[(k >> 5) * 512 + (((k >> 3) & 3) * 16 + c) * 8 + (k & 7)] = f2h(Creg0[r]);
        Cbf[1024 + (k >> 5) * 512 + (((k >> 3) & 3) * 16 + c) * 8 + (k & 7)] = f2h(Creg1[r]);
      }
    }
  }
  __syncthreads();

  const int hq = lane & 31;
  const int sp = lane >> 5;                 // sample-half: 0 -> sgrp0 (lo), 1 -> sgrp1 (hi)
  const unsigned int sh = sp * 16;          // f16 half-select shift
  const int esb = 4 * sp;
  const float ea0 = alpha[bg + esb + 0], ea1 = alpha[bg + esb + 1];
  const float ea2 = alpha[bg + esb + 2], ea3 = alpha[bg + esb + 3];
  const float eb0 = beta[bg + esb + 0],  eb1 = beta[bg + esb + 1];
  const float eb2 = beta[bg + esb + 2],  eb3 = beta[bg + esb + 3];
  const float* er0 = R_U + (size_t)(bg + esb + 0) * (HH * 3);
  const float* er1 = R_U + (size_t)(bg + esb + 1) * (HH * 3);
  const float* er2 = R_U + (size_t)(bg + esb + 2) * (HH * 3);
  const float* er3 = R_U + (size_t)(bg + esb + 3) * (HH * 3);

  unsigned short* Pbh = pool + wid * SLICE;   // wave slice base
  unsigned int*   Pw32 = (unsigned int*)Pbh;  // dword view: [32 h][PbStrD]
  unsigned short* Gbu = pool + wid * SLICE;   // bf16 [24 c][GbStr]  (aliases Pb)

  for (int it = 0; it < 3; ++it) {
    f32x4 g00 = {0.f,0.f,0.f,0.f}, g01 = {0.f,0.f,0.f,0.f};
    f32x4 g10 = {0.f,0.f,0.f,0.f}, g11 = {0.f,0.f,0.f,0.f};
    f32x4 g20 = {0.f,0.f,0.f,0.f}, g21 = {0.f,0.f,0.f,0.f};
    f32x4 g30 = {0.f,0.f,0.f,0.f}, g31 = {0.f,0.f,0.f,0.f};

    f16x8 cf00 = *(const f16x8*)&Cbf[lane * 8];
    f16x8 cf01 = *(const f16x8*)&Cbf[512 + lane * 8];
    f16x8 cf10 = *(const f16x8*)&Cbf[1024 + lane * 8];
    f16x8 cf11 = *(const f16x8*)&Cbf[1536 + lane * 8];

    for (int q = 0; q < 4; ++q) {
      asm volatile("" ::: "memory");   // fence: fwd stores stay after prev bwd loads

      // ---- forward: 8 A-tiles (2 ht x 4 z) x 2 sgrp; packed dword stores ----
      #pragma unroll
      for (int ht = 0; ht < 2; ++ht) {
        const int htg = wid * 8 + q * 2 + ht;
        #pragma unroll
        for (int z = 0; z < 4; ++z) {
          const unsigned short* pA =
              AFf + (size_t)((z * 32 + htg) * 2) * 512 + lane * 8;
          f16x8 af0 = *(const f16x8*)pA;
          f16x8 af1 = *(const f16x8*)(pA + 512);
          __builtin_amdgcn_s_setprio(1);
          f32x4 d0 = {0.f, 0.f, 0.f, 0.f};
          d0 = __builtin_amdgcn_mfma_f32_16x16x32_f16(af0, cf00, d0, 0, 0, 0);
          d0 = __builtin_amdgcn_mfma_f32_16x16x32_f16(af1, cf01, d0, 0, 0, 0);
          f32x4 d1 = {0.f, 0.f, 0.f, 0.f};
          d1 = __builtin_amdgcn_mfma_f32_16x16x32_f16(af0, cf10, d1, 0, 0, 0);
          d1 = __builtin_amdgcn_mfma_f32_16x16x32_f16(af1, cf11, d1, 0, 0, 0);
          __builtin_amdgcn_s_setprio(0);
          if (c < 12) {
            unsigned int* Pw = Pw32 + (ht * 16 + quad * 4) * PbStrD
                                    + sl * 12 + z * 3 + fm;
            Pw[0 * PbStrD] = (unsigned)f2h(d0[0]) | ((unsigned)f2h(d1[0]) << 16);
            Pw[1 * PbStrD] = (unsigned)f2h(d0[1]) | ((unsigned)f2h(d1[1]) << 16);
            Pw[2 * PbStrD] = (unsigned)f2h(d0[2]) | ((unsigned)f2h(d1[2]) << 16);
            Pw[3 * PbStrD] = (unsigned)f2h(d0[3]) | ((unsigned)f2h(d1[3]) << 16);
          }
        }
      }

      // ---- elementwise: 32 h x (4 samples via half-select), b128 loads ----
      {
        const unsigned int* Pr = (const unsigned int*)Pw32 + hq * PbStrD;
        u32x4 wa0 = *(const u32x4*)(Pr + 0);
        u32x4 wa1 = *(const u32x4*)(Pr + 4);
        u32x4 wa2 = *(const u32x4*)(Pr + 8);
        u32x4 wb0 = *(const u32x4*)(Pr + 12);
        u32x4 wb1 = *(const u32x4*)(Pr + 16);
        u32x4 wb2 = *(const u32x4*)(Pr + 20);
        u32x4 wc0 = *(const u32x4*)(Pr + 24);
        u32x4 wc1 = *(const u32x4*)(Pr + 28);
        u32x4 wc2 = *(const u32x4*)(Pr + 32);
        u32x4 wd0 = *(const u32x4*)(Pr + 36);
        u32x4 wd1 = *(const u32x4*)(Pr + 40);
        u32x4 wd2 = *(const u32x4*)(Pr + 44);
        const int hg = wid * 128 + q * 32 + hq;
        float r00 = er0[(size_t)hg*3], r01 = er0[(size_t)hg*3+1], r02 = er0[(size_t)hg*3+2];
        float r10 = er1[(size_t)hg*3], r11 = er1[(size_t)hg*3+1], r12 = er1[(size_t)hg*3+2];
        float r20 = er2[(size_t)hg*3], r21 = er2[(size_t)hg*3+1], r22 = er2[(size_t)hg*3+2];
        float r30 = er3[(size_t)hg*3], r31 = er3[(size_t)hg*3+1], r32 = er3[(size_t)hg*3+2];
        asm volatile("" ::: "memory");   // fence: Gb stores stay after Pb loads

        float gA0,gA1,gA2,gA3,gA4,gA5,gA6,gA7,gA8,gA9,gA10,gA11;
        float gB0,gB1,gB2,gB3,gB4,gB5,gB6,gB7,gB8,gB9,gB10,gB11;
        elemf(hsel(wa0[0],sh),hsel(wa0[1],sh),hsel(wa0[2],sh),hsel(wa0[3],sh),
              hsel(wa1[0],sh),hsel(wa1[1],sh),hsel(wa1[2],sh),hsel(wa1[3],sh),
              hsel(wa2[0],sh),hsel(wa2[1],sh),hsel(wa2[2],sh),hsel(wa2[3],sh),
              ea0, eb0, r00, r01, r02, l1, l2, l3,
              gA0,gA1,gA2,gA3,gA4,gA5,gA6,gA7,gA8,gA9,gA10,gA11);
        elemf(hsel(wb0[0],sh),hsel(wb0[1],sh),hsel(wb0[2],sh),hsel(wb0[3],sh),
              hsel(wb1[0],sh),hsel(wb1[1],sh),hsel(wb1[2],sh),hsel(wb1[3],sh),
              hsel(wb2[0],sh),hsel(wb2[1],sh),hsel(wb2[2],sh),hsel(wb2[3],sh),
              ea1, eb1, r10, r11, r12, l1, l2, l3,
              gB0,gB1,gB2,gB3,gB4,gB5,gB6,gB7,gB8,gB9,gB10,gB11);

        #define STOREG(zz, mm, GA, GB, E0, E1) { \
          unsigned int pk = pkbf2(GA, GB); \
          Gbu[(3*(esb+E0) + mm) * GbStr + (zz)*32 + hq] = (unsigned short)pk; \
          Gbu[(3*(esb+E1) + mm) * GbStr + (zz)*32 + hq] = (unsigned short)(pk >> 16); }
        STOREG(0, 0, gA0, gB0, 0, 1)  STOREG(0, 1, gA1, gB1, 0, 1)  STOREG(0, 2, gA2, gB2, 0, 1)
        STOREG(1, 0, gA3, gB3, 0, 1)  STOREG(1, 1, gA4, gB4, 0, 1)  STOREG(1, 2, gA5, gB5, 0, 1)
        STOREG(2, 0, gA6, gB6, 0, 1)  STOREG(2, 1, gA7, gB7, 0, 1)  STOREG(2, 2, gA8, gB8, 0, 1)
        STOREG(3, 0, gA9, gB9, 0, 1)  STOREG(3, 1, gA10, gB10, 0, 1) STOREG(3, 2, gA11, gB11, 0, 1)

        elemf(hsel(wc0[0],sh),hsel(wc0[1],sh),hsel(wc0[2],sh),hsel(wc0[3],sh),
              hsel(wc1[0],sh),hsel(wc1[1],sh),hsel(wc1[2],sh),hsel(wc1[3],sh),
              hsel(wc2[0],sh),hsel(wc2[1],sh),hsel(wc2[2],sh),hsel(wc2[3],sh),
              ea2, eb2, r20, r21, r22, l1, l2, l3,
              gA0,gA1,gA2,gA3,gA4,gA5,gA6,gA7,gA8,gA9,gA10,gA11);
        elemf(hsel(wd0[0],sh),hsel(wd0[1],sh),hsel(wd0[2],sh),hsel(wd0[3],sh),
              hsel(wd1[0],sh),hsel(wd1[1],sh),hsel(wd1[2],sh),hsel(wd1[3],sh),
              hsel(wd2[0],sh),hsel(wd2[1],sh),hsel(wd2[2],sh),hsel(wd2[3],sh),
              ea3, eb3, r30, r31, r32, l1, l2, l3,
              gB0,gB1,gB2,gB3,gB4,gB5,gB6,gB7,gB8,gB9,gB10,gB11);
        STOREG(0, 0, gA0, gB0, 2, 3)  STOREG(0, 1, gA1, gB1, 2, 3)  STOREG(0, 2, gA2, gB2, 2, 3)
        STOREG(1, 0, gA3, gB3, 2, 3)  STOREG(1, 1, gA4, gB4, 2, 3)  STOREG(1, 2, gA5, gB5, 2, 3)
        STOREG(2, 0, gA6, gB6, 2, 3)  STOREG(2, 1, gA7, gB7, 2, 3)  STOREG(2, 2, gA8, gB8, 2, 3)
        STOREG(3, 0, gA9, gB9, 2, 3)  STOREG(3, 1, gA10, gB10, 2, 3) STOREG(3, 2, gA11, gB11, 2, 3)
        #undef STOREG
      }

      // ---- backward partial: 4 m-tiles x 2 sgrp over this wave's h-slice ----
      __builtin_amdgcn_s_setprio(1);
      #pragma unroll
      for (int ks2 = 0; ks2 < 4; ++ks2) {
        bf16x8 gg0 = *(const bf16x8*)&Gbu[c * GbStr + ks2 * 32 + quad * 8];
        bf16x8 gg1 = *(const bf16x8*)&Gbu[(12 + c) * GbStr + ks2 * 32 + quad * 8];
        const unsigned short* pA0 =
            AFb + (size_t)(((wid * 4 + q) * 4 + ks2) * 4) * 512 + lane * 8;
        bf16x8 a0 = *(const bf16x8*)(pA0);
        bf16x8 a1 = *(const bf16x8*)(pA0 + 512);
        bf16x8 a2 = *(const bf16x8*)(pA0 + 1024);
        bf16x8 a3 = *(const bf16x8*)(pA0 + 1536);
        g00 = __builtin_amdgcn_mfma_f32_16x16x32_bf16(a0, gg0, g00, 0, 0, 0);
        g01 = __builtin_amdgcn_mfma_f32_16x16x32_bf16(a0, gg1, g01, 0, 0, 0);
        g10 = __builtin_amdgcn_mfma_f32_16x16x32_bf16(a1, gg0, g10, 0, 0, 0);
        g11 = __builtin_amdgcn_mfma_f32_16x16x32_bf16(a1, gg1, g11, 0, 0, 0);
        g20 = __builtin_amdgcn_mfma_f32_16x16x32_bf16(a2, gg0, g20, 0, 0, 0);
        g21 = __builtin_amdgcn_mfma_f32_16x16x32_bf16(a2, gg1, g21, 0, 0, 0);
        g30 = __builtin_amdgcn_mfma_f32_16x16x32_bf16(a3, gg0, g30, 0, 0, 0);
        g31 = __builtin_amdgcn_mfma_f32_16x16x32_bf16(a3, gg1, g31, 0, 0, 0);
      }
      __builtin_amdgcn_s_setprio(0);
    }

    // ---- dump partials into OWN slice, reduce, update C (registers) ----
    {
      float* dmp = (float*)pool + wid * (SLICE / 2);
      *(f32x4*)(dmp +    0 + lane * 4) = g00;
      *(f32x4*)(dmp +  256 + lane * 4) = g01;
      *(f32x4*)(dmp +  512 + lane * 4) = g10;
      *(f32x4*)(dmp +  768 + lane * 4) = g11;
      *(f32x4*)(dmp + 1024 + lane * 4) = g20;
      *(f32x4*)(dmp + 1280 + lane * 4) = g21;
      *(f32x4*)(dmp + 1536 + lane * 4) = g30;
      *(f32x4*)(dmp + 1792 + lane * 4) = g31;
    }
    __syncthreads();
    {
      const float* poolF = (const float*)pool;
      f32x4 tot0 = {0.f, 0.f, 0.f, 0.f};
      f32x4 tot1 = {0.f, 0.f, 0.f, 0.f};
      #pragma unroll
      for (int v = 0; v < 4; ++v) {
        tot0 += *(const f32x4*)(poolF + v * (SLICE / 2) + (wid * 2 + 0) * 256 + lane * 4);
        tot1 += *(const f32x4*)(poolF + v * (SLICE / 2) + (wid * 2 + 1) * 256 + lane * 4);
      }
      Creg0 -= LR * tot0;
      Creg1 -= LR * tot1;
      if (c < 12 && it < 2) {
        #pragma unroll
        for (int r = 0; r < 4; ++r) {
          int k = kr + r;
          Cbf[(k >> 5) * 512 + (((k >> 3) & 3) * 16 + c) * 8 + (k & 7)] = f2h(Creg0[r]);
          Cbf[1024 + (k >> 5) * 512 + (((k >> 3) & 3) * 16 + c) * 8 + (k & 7)] = f2h(Creg1[r]);
        }
      }
    }
    __syncthreads();
  }

  // ---- stage final C -> pool fp32 [s][k][m], then coalesced out ----
  {
    float* poolF = (float*)pool;
    if (c < 12) {
      #pragma unroll
      for (int r = 0; r < 4; ++r) {
        int k = kr + r;
        poolF[sl * OutStr + k * 3 + fm]       = Creg0[r];
        poolF[(sl + 4) * OutStr + k * 3 + fm] = Creg1[r];
      }
    }
  }
  __syncthreads();
  {
    const float* poolF = (const float*)pool;
    #pragma unroll
    for (int sg2 = 0; sg2 < 2; ++sg2) {
      const int ps = wid + sg2 * 4;
      float* op = out + ((size_t)(bg + ps) * KK + lane) * 3;
      op[0] = poolF[ps * OutStr + lane * 3 + 0];
      op[1] = poolF[ps * OutStr + lane * 3 + 1];
      op[2] = poolF[ps * OutStr + lane * 3 + 2];
    }
  }
}

extern "C" void kernel_launch(void* const* d_in, const int* in_sizes, int n_in,
                              void* d_out, int out_size, void* d_ws, size_t ws_size,
                              hipStream_t stream) {
  const float* R_U     = (const float*)d_in[0];
  const float* alpha   = (const float*)d_in[1];
  const float* beta    = (const float*)d_in[2];
  const float* lambdas = (const float*)d_in[3];
  const float* B       = (const float*)d_in[4];
  const float* Bd      = (const float*)d_in[5];
  const float* Bdd     = (const float*)d_in[6];
  const float* Bddd    = (const float*)d_in[7];
  const float* Bp      = (const float*)d_in[8];
  unsigned short* ws = (unsigned short*)d_ws;
  const int nB = in_sizes[1];   // 16384

  hipLaunchKernelGGL(prep_kernel, dim3(640), dim3(256), 0, stream,
                     B, Bd, Bdd, Bddd, Bp, ws);
  hipLaunchKernelGGL(copt_kernel, dim3(nB / SS), dim3(256), 0, stream,
                     R_U, alpha, beta, lambdas, ws, (float*)d_out);
}

// Round 11
// 368.147 us; speedup vs baseline: 1.1094x; 1.1094x over previous
//
#include <hip/hip_runtime.h>
#include <hip/hip_bf16.h>
#include <math.h>

#define EPSF 1e-8f
#define LR   1e-3f

#define HH 512
#define KK 64
#define SS 8          // samples per block (4 waves x 2 sample-groups)
#define PbStr 100     // Pb row stride (ush): 96 data + 4 pad (50 dwords, gcd(50,32)=2)
#define GbStr 136     // Gb col stride (ush): 128 K + 8 pad
#define SLICE 4096    // per-wave slice (ush) = 8192 B (dump: 8 accs x 1KB)
#define OutStr 193    // pool fp32 out-stage stride (floats) per sample

typedef short    bf16x8 __attribute__((ext_vector_type(8)));
typedef _Float16 f16x8  __attribute__((ext_vector_type(8)));
typedef _Float16 f16x4  __attribute__((ext_vector_type(4)));
typedef float    f32x4  __attribute__((ext_vector_type(4)));

__device__ __forceinline__ unsigned short f2bf(float x) {
  unsigned int u = __float_as_uint(x);
  return (unsigned short)((u + 0x7fffu + ((u >> 16) & 1u)) >> 16);
}
__device__ __forceinline__ float bfhi(float x) {
  return __uint_as_float(((unsigned int)f2bf(x)) << 16);
}
__device__ __forceinline__ unsigned short f2h(float x) {
  _Float16 h = (_Float16)x;
  return *(unsigned short*)&h;
}
__device__ __forceinline__ unsigned int pkbf2(float a, float b) {
  union { __hip_bfloat162 h; unsigned int u; } cv;
  cv.h = __float22bfloat162_rn(make_float2(a, b));
  return cv.u;
}

// elementwise gradient, all-scalar (no arrays -> guaranteed SROA)
__device__ __forceinline__ void elemf(
    float P0, float P1, float P2, float V0, float V1, float V2,
    float A0, float A1, float A2, float J0, float J1, float J2,
    float aa, float bb, float r0, float r1, float r2,
    float l1, float l2, float l3,
    float& o0, float& o1, float& o2, float& o3, float& o4, float& o5,
    float& o6, float& o7, float& o8, float& o9, float& o10, float& o11) {
  float v2 = V0*V0 + V1*V1 + V2*V2;
  float v  = __builtin_amdgcn_sqrtf(v2);
  float ve = v + EPSF;
  float cx0 = V1*A2 - V2*A1;
  float cx1 = V2*A0 - V0*A2;
  float cx2 = V0*A1 - V1*A0;
  float nc  = __builtin_amdgcn_sqrtf(cx0*cx0 + cx1*cx1 + cx2*cx2);
  float ve2 = ve*ve;
  float denom = ve2*ve + EPSF;
  float invd  = __builtin_amdgcn_rcpf(denom);
  float kappa = nc * invd;
  float ks  = fminf(fmaxf(kappa, 1e-4f), 1e4f);
  float lpr = bb * __logf(ks);
  float lp  = fminf(fmaxf(lpr, -10.f), 10.f);
  float tr  = aa * __expf(lp);
  float tt  = fminf(fmaxf(tr, 1e-6f), 1e6f);
  float s2  = 2.f*l2*(v - tt);
  float gtr  = (tr > 1e-6f && tr < 1e6f) ? -s2 : 0.f;
  float glpr = (lpr > -10.f && lpr < 10.f) ? gtr*tr : 0.f;
  float gk   = (kappa > 1e-4f && kappa < 1e4f)
                 ? glpr*bb*__builtin_amdgcn_rcpf(ks) : 0.f;
  float gnc  = gk * invd;
  float gden = -gk * kappa * invd;
  float gve  = 3.f * ve2 * gden;
  float gv   = s2 + gve;
  float giv  = gv * __builtin_amdgcn_rcpf(v);
  float gcs  = gnc * __builtin_amdgcn_rcpf(nc);
  float gc0 = gcs*cx0, gc1 = gcs*cx1, gc2 = gcs*cx2;
  o0  = 2.f*l1*(P0 - r0);
  o1  = 2.f*l1*(P1 - r1);
  o2  = 2.f*l1*(P2 - r2);
  o3  = fmaf(giv, V0, A1*gc2 - A2*gc1);
  o4  = fmaf(giv, V1, A2*gc0 - A0*gc2);
  o5  = fmaf(giv, V2, A0*gc1 - A1*gc0);
  o6  = gc1*V2 - gc2*V1;
  o7  = gc2*V0 - gc0*V2;
  o8  = gc0*V1 - gc1*V0;
  o9  = 2.f*l3*J0;
  o10 = 2.f*l3*J1;
  o11 = 2.f*l3*J2;
}

// ws layout (ushort units) — UNCHANGED:
//  AFb @ 0      (131072): bwd A-frags, single bf16
//  AFf @ 131072 (131072): fwd A-frags fp16
//  AFp @ 262144 (65536): C0 A-frags bf16 hi/lo (Bp)
__global__ void prep_kernel(const float* __restrict__ B,
                            const float* __restrict__ Bd,
                            const float* __restrict__ Bdd,
                            const float* __restrict__ Bddd,
                            const float* __restrict__ Bp,
                            unsigned short* __restrict__ ws) {
  int tid = blockIdx.x * 256 + threadIdx.x;   // 640 * 256 = 163840
  const float* Ms[4] = {B, Bd, Bdd, Bddd};
  unsigned short bits[2];
  if (tid < 65536) {
    #pragma unroll
    for (int t = 0; t < 2; ++t) {
      unsigned int id = 2u * tid + t;
      int j = id & 7, lane = (id >> 3) & 63;
      int mt = (id >> 9) & 3, ks2 = (id >> 11) & 3;
      int qtr = (id >> 13) & 3, chunk = (id >> 15) & 3;
      int khat = mt * 16 + (lane & 15);
      int kq = ((lane >> 4) << 3) + j;
      int h = chunk * 128 + qtr * 32 + kq;
      bits[t] = f2bf(Ms[ks2][h * 64 + khat]);
    }
    ((unsigned int*)ws)[tid] = ((unsigned int)bits[1] << 16) | bits[0];
  } else if (tid < 131072) {
    int base = tid - 65536;
    #pragma unroll
    for (int t = 0; t < 2; ++t) {
      unsigned int id = 2u * base + t;
      int j = id & 7, lane = (id >> 3) & 63, kap = (id >> 9) & 1;
      int ht = (id >> 10) & 31, z = (id >> 15) & 3;
      int h = ht * 16 + (lane & 15);
      int kk = kap * 32 + ((lane >> 4) << 3) + j;
      bits[t] = f2h(Ms[z][h * 64 + kk]);
    }
    ((unsigned int*)(ws + 131072))[base] = ((unsigned int)bits[1] << 16) | bits[0];
  } else {
    int base = tid - 131072;
    #pragma unroll
    for (int t = 0; t < 2; ++t) {
      unsigned int id = 2u * base + t;
      int j = id & 7, lane = (id >> 3) & 63, hilo = (id >> 9) & 1;
      int mt = (id >> 10) & 3, ks = (id >> 12) & 15;
      int khat = mt * 16 + (lane & 15);
      int Kl = ks * 32 + ((lane >> 4) << 3) + j;
      float val = Bp[khat * 512 + Kl];
      float hi = bfhi(val);
      bits[t] = hilo ? f2bf(val - hi) : f2bf(hi);
    }
    ((unsigned int*)(ws + 262144))[base] = ((unsigned int)bits[1] << 16) | bits[0];
  }
}

// Best-measured configuration (r7: copt 277.8us, total 368.5us).
// SS=8, 4 waves, LDS 36KB, register-resident C, PbStr=100, min-waves=3.
// Levers measured and rejected: forcing 4 blk/CU (spills, r3/r8), packed-Pb
// (spills, r10), r-hoist (+FETCH, r9), bank-conflict pad (not binding),
// setprio (neutral, kept). Kernel is latency-bound at 31% occupancy with
// liveness ~148 regs/wave; further gains need a producer-consumer wave split.
__global__ __launch_bounds__(256, 3)
void copt_kernel(const float* __restrict__ R_U,
                 const float* __restrict__ alpha,
                 const float* __restrict__ beta,
                 const float* __restrict__ lambdas,
                 const unsigned short* __restrict__ ws,
                 float* __restrict__ out) {
  __shared__ __align__(16) unsigned short Cbf[2 * 1024];   // 4 KB fp16 C B-frags
  __shared__ __align__(16) unsigned short pool[4 * SLICE]; // 32 KB per-wave Pb/Gb/dump

  const unsigned short* AFb = ws;
  const unsigned short* AFf = ws + 131072;
  const unsigned short* AFp = ws + 262144;

  const int tid  = threadIdx.x;
  const int lane = tid & 63;
  const int wid  = tid >> 6;
  const int quad = lane >> 4;
  const int c    = lane & 15;

  const float l1 = lambdas[0], l2 = lambdas[1], l3 = lambdas[2];
  const int bg = blockIdx.x * SS;

  ((float4*)Cbf)[tid] = make_float4(0.f, 0.f, 0.f, 0.f);  // cols 12..15 stay 0

  // ---- stage r -> pool (bf16): [col = sg2*12 + 3*wid + m][h], stride 520 ----
  #pragma unroll
  for (int sg2 = 0; sg2 < 2; ++sg2) {
    const int colb = sg2 * 12 + 3 * wid;
    const float4* rp = (const float4*)(R_U + (size_t)(bg + wid + sg2 * 4) * (HH * 3));
    #pragma unroll
    for (int i = 0; i < 6; ++i) {
      float4 v = rp[i * 64 + lane];
      int e = (i * 64 + lane) * 4;
      const float* pv = &v.x;
      #pragma unroll
      for (int d = 0; d < 4; ++d) {
        int ee = e + d, h = ee / 3, m = ee - 3 * h;
        pool[(colb + m) * 520 + h] = f2bf(pv[d]);
      }
    }
  }
  __syncthreads();

  // C register state: c<12 lanes own C[sl][wid*16+quad*4+r][m] (Creg0) and
  // C[sl+4][...][m] (Creg1). Other lanes carry dead values.
  f32x4 Creg0 = {0.f, 0.f, 0.f, 0.f};
  f32x4 Creg1 = {0.f, 0.f, 0.f, 0.f};
  const int sl = (c * 86) >> 8, fm = c - 3 * sl;     // sample-in-group, m
  const int kr = wid * 16 + quad * 4;

  // ---- C0 = Bp @ r via MFMA (bf16 hi/lo A, bf16 r); this wave: mt = wid ----
  {
    const unsigned short* gb0 = &pool[c * 520 + quad * 8];
    const unsigned short* gb1 = &pool[(12 + c) * 520 + quad * 8];
    __builtin_amdgcn_s_setprio(1);
    #pragma unroll 4
    for (int ks = 0; ks < 16; ++ks) {
      const unsigned short* pA = AFp + (size_t)((ks * 4 + wid) * 2) * 512 + lane * 8;
      bf16x8 ah = *(const bf16x8*)pA;
      bf16x8 al = *(const bf16x8*)(pA + 512);
      bf16x8 g0 = *(const bf16x8*)(gb0 + ks * 32);
      bf16x8 g1 = *(const bf16x8*)(gb1 + ks * 32);
      Creg0 = __builtin_amdgcn_mfma_f32_16x16x32_bf16(ah, g0, Creg0, 0, 0, 0);
      Creg0 = __builtin_amdgcn_mfma_f32_16x16x32_bf16(al, g0, Creg0, 0, 0, 0);
      Creg1 = __builtin_amdgcn_mfma_f32_16x16x32_bf16(ah, g1, Creg1, 0, 0, 0);
      Creg1 = __builtin_amdgcn_mfma_f32_16x16x32_bf16(al, g1, Creg1, 0, 0, 0);
    }
    __builtin_amdgcn_s_setprio(0);
    if (c < 12) {
      #pragma unroll
      for (int r = 0; r < 4; ++r) {
        int k = kr + r;
        Cbf[(k >> 5) * 512 + (((k >> 3) & 3) * 16 + c) * 8 + (k & 7)] = f2h(Creg0[r]);
        Cbf[1024 + (k >> 5) * 512 + (((k >> 3) & 3) * 16 + c) * 8 + (k & 7)] = f2h(Creg1[r]);
      }
    }
  }
  __syncthreads();

  // elem thread ids: h = hq (lane&31); lane-half picks sample quartet
  const int hq = lane & 31;
  const int esb = 4 * (lane >> 5);               // 0 or 4
  const float ea0 = alpha[bg + esb + 0], ea1 = alpha[bg + esb + 1];
  const float ea2 = alpha[bg + esb + 2], ea3 = alpha[bg + esb + 3];
  const float eb0 = beta[bg + esb + 0],  eb1 = beta[bg + esb + 1];
  const float eb2 = beta[bg + esb + 2],  eb3 = beta[bg + esb + 3];
  const float* er0 = R_U + (size_t)(bg + esb + 0) * (HH * 3);
  const float* er1 = R_U + (size_t)(bg + esb + 1) * (HH * 3);
  const float* er2 = R_U + (size_t)(bg + esb + 2) * (HH * 3);
  const float* er3 = R_U + (size_t)(bg + esb + 3) * (HH * 3);

  unsigned short* Pbh = pool + wid * SLICE;   // fp16 [32 h][PbStr]: col = s*12+z*3+m
  unsigned short* Gbu = pool + wid * SLICE;   // bf16 [24 c][GbStr]  (aliases Pbh)

  for (int it = 0; it < 3; ++it) {
    f32x4 g00 = {0.f,0.f,0.f,0.f}, g01 = {0.f,0.f,0.f,0.f};
    f32x4 g10 = {0.f,0.f,0.f,0.f}, g11 = {0.f,0.f,0.f,0.f};
    f32x4 g20 = {0.f,0.f,0.f,0.f}, g21 = {0.f,0.f,0.f,0.f};
    f32x4 g30 = {0.f,0.f,0.f,0.f}, g31 = {0.f,0.f,0.f,0.f};

    f16x8 cf00 = *(const f16x8*)&Cbf[lane * 8];
    f16x8 cf01 = *(const f16x8*)&Cbf[512 + lane * 8];
    f16x8 cf10 = *(const f16x8*)&Cbf[1024 + lane * 8];
    f16x8 cf11 = *(const f16x8*)&Cbf[1536 + lane * 8];

    for (int q = 0; q < 4; ++q) {
      // ---- forward: 8 A-tiles (2 ht x 4 z) x 2 sgrp, wave-local ----
      #pragma unroll
      for (int ht = 0; ht < 2; ++ht) {
        const int htg = wid * 8 + q * 2 + ht;
        #pragma unroll
        for (int z = 0; z < 4; ++z) {
          const unsigned short* pA =
              AFf + (size_t)((z * 32 + htg) * 2) * 512 + lane * 8;
          f16x8 af0 = *(const f16x8*)pA;
          f16x8 af1 = *(const f16x8*)(pA + 512);
          __builtin_amdgcn_s_setprio(1);
          f32x4 d0 = {0.f, 0.f, 0.f, 0.f};
          d0 = __builtin_amdgcn_mfma_f32_16x16x32_f16(af0, cf00, d0, 0, 0, 0);
          d0 = __builtin_amdgcn_mfma_f32_16x16x32_f16(af1, cf01, d0, 0, 0, 0);
          f32x4 d1 = {0.f, 0.f, 0.f, 0.f};
          d1 = __builtin_amdgcn_mfma_f32_16x16x32_f16(af0, cf10, d1, 0, 0, 0);
          d1 = __builtin_amdgcn_mfma_f32_16x16x32_f16(af1, cf11, d1, 0, 0, 0);
          __builtin_amdgcn_s_setprio(0);
          if (c < 12) {
            unsigned short* pb = Pbh + (ht * 16 + quad * 4) * PbStr + z * 3 + fm;
            unsigned short* pp0 = pb + sl * 12;
            pp0[0 * PbStr] = f2h(d0[0]);
            pp0[1 * PbStr] = f2h(d0[1]);
            pp0[2 * PbStr] = f2h(d0[2]);
            pp0[3 * PbStr] = f2h(d0[3]);
            unsigned short* pp1 = pb + (sl + 4) * 12;
            pp1[0 * PbStr] = f2h(d1[0]);
            pp1[1 * PbStr] = f2h(d1[1]);
            pp1[2 * PbStr] = f2h(d1[2]);
            pp1[3 * PbStr] = f2h(d1[3]);
          }
        }
      }

      // ---- elementwise: this wave's 32 h, thread = (h, sample quartet) ----
      {
        // load ALL P values before any Gb store (Gb aliases Pb!)
        const unsigned short* p0 = Pbh + hq * PbStr + (esb + 0) * 12;
        const unsigned short* p1 = Pbh + hq * PbStr + (esb + 1) * 12;
        const unsigned short* p2 = Pbh + hq * PbStr + (esb + 2) * 12;
        const unsigned short* p3 = Pbh + hq * PbStr + (esb + 3) * 12;
        f16x4 va0 = *(const f16x4*)(p0);
        f16x4 va1 = *(const f16x4*)(p0 + 4);
        f16x4 va2 = *(const f16x4*)(p0 + 8);
        f16x4 vb0 = *(const f16x4*)(p1);
        f16x4 vb1 = *(const f16x4*)(p1 + 4);
        f16x4 vb2 = *(const f16x4*)(p1 + 8);
        f16x4 vc0 = *(const f16x4*)(p2);
        f16x4 vc1 = *(const f16x4*)(p2 + 4);
        f16x4 vc2 = *(const f16x4*)(p2 + 8);
        f16x4 vd0 = *(const f16x4*)(p3);
        f16x4 vd1 = *(const f16x4*)(p3 + 4);
        f16x4 vd2 = *(const f16x4*)(p3 + 8);
        const int hg = wid * 128 + q * 32 + hq;
        float r00 = er0[(size_t)hg*3], r01 = er0[(size_t)hg*3+1], r02 = er0[(size_t)hg*3+2];
        float r10 = er1[(size_t)hg*3], r11 = er1[(size_t)hg*3+1], r12 = er1[(size_t)hg*3+2];
        float r20 = er2[(size_t)hg*3], r21 = er2[(size_t)hg*3+1], r22 = er2[(size_t)hg*3+2];
        float r30 = er3[(size_t)hg*3], r31 = er3[(size_t)hg*3+1], r32 = er3[(size_t)hg*3+2];

        float gA0,gA1,gA2,gA3,gA4,gA5,gA6,gA7,gA8,gA9,gA10,gA11;
        float gB0,gB1,gB2,gB3,gB4,gB5,gB6,gB7,gB8,gB9,gB10,gB11;
        elemf((float)va0[0],(float)va0[1],(float)va0[2],(float)va0[3],
              (float)va1[0],(float)va1[1],(float)va1[2],(float)va1[3],
              (float)va2[0],(float)va2[1],(float)va2[2],(float)va2[3],
              ea0, eb0, r00, r01, r02, l1, l2, l3,
              gA0,gA1,gA2,gA3,gA4,gA5,gA6,gA7,gA8,gA9,gA10,gA11);
        elemf((float)vb0[0],(float)vb0[1],(float)vb0[2],(float)vb0[3],
              (float)vb1[0],(float)vb1[1],(float)vb1[2],(float)vb1[3],
              (float)vb2[0],(float)vb2[1],(float)vb2[2],(float)vb2[3],
              ea1, eb1, r10, r11, r12, l1, l2, l3,
              gB0,gB1,gB2,gB3,gB4,gB5,gB6,gB7,gB8,gB9,gB10,gB11);

        #define STOREG(zz, mm, GA, GB, E0, E1) { \
          unsigned int pk = pkbf2(GA, GB); \
          Gbu[(3*(esb+E0) + mm) * GbStr + (zz)*32 + hq] = (unsigned short)pk; \
          Gbu[(3*(esb+E1) + mm) * GbStr + (zz)*32 + hq] = (unsigned short)(pk >> 16); }
        STOREG(0, 0, gA0, gB0, 0, 1)  STOREG(0, 1, gA1, gB1, 0, 1)  STOREG(0, 2, gA2, gB2, 0, 1)
        STOREG(1, 0, gA3, gB3, 0, 1)  STOREG(1, 1, gA4, gB4, 0, 1)  STOREG(1, 2, gA5, gB5, 0, 1)
        STOREG(2, 0, gA6, gB6, 0, 1)  STOREG(2, 1, gA7, gB7, 0, 1)  STOREG(2, 2, gA8, gB8, 0, 1)
        STOREG(3, 0, gA9, gB9, 0, 1)  STOREG(3, 1, gA10, gB10, 0, 1) STOREG(3, 2, gA11, gB11, 0, 1)

        elemf((float)vc0[0],(float)vc0[1],(float)vc0[2],(float)vc0[3],
              (float)vc1[0],(float)vc1[1],(float)vc1[2],(float)vc1[3],
              (float)vc2[0],(float)vc2[1],(float)vc2[2],(float)vc2[3],
              ea2, eb2, r20, r21, r22, l1, l2, l3,
              gA0,gA1,gA2,gA3,gA4,gA5,gA6,gA7,gA8,gA9,gA10,gA11);
        elemf((float)vd0[0],(float)vd0[1],(float)vd0[2],(float)vd0[3],
              (float)vd1[0],(float)vd1[1],(float)vd1[2],(float)vd1[3],
              (float)vd2[0],(float)vd2[1],(float)vd2[2],(float)vd2[3],
              ea3, eb3, r30, r31, r32, l1, l2, l3,
              gB0,gB1,gB2,gB3,gB4,gB5,gB6,gB7,gB8,gB9,gB10,gB11);
        STOREG(0, 0, gA0, gB0, 2, 3)  STOREG(0, 1, gA1, gB1, 2, 3)  STOREG(0, 2, gA2, gB2, 2, 3)
        STOREG(1, 0, gA3, gB3, 2, 3)  STOREG(1, 1, gA4, gB4, 2, 3)  STOREG(1, 2, gA5, gB5, 2, 3)
        STOREG(2, 0, gA6, gB6, 2, 3)  STOREG(2, 1, gA7, gB7, 2, 3)  STOREG(2, 2, gA8, gB8, 2, 3)
        STOREG(3, 0, gA9, gB9, 2, 3)  STOREG(3, 1, gA10, gB10, 2, 3) STOREG(3, 2, gA11, gB11, 2, 3)
        #undef STOREG
      }

      // ---- backward partial: 4 m-tiles x 2 sgrp over this wave's h-slice ----
      __builtin_amdgcn_s_setprio(1);
      #pragma unroll
      for (int ks2 = 0; ks2 < 4; ++ks2) {
        bf16x8 gg0 = *(const bf16x8*)&Gbu[c * GbStr + ks2 * 32 + quad * 8];
        bf16x8 gg1 = *(const bf16x8*)&Gbu[(12 + c) * GbStr + ks2 * 32 + quad * 8];
        const unsigned short* pA0 =
            AFb + (size_t)(((wid * 4 + q) * 4 + ks2) * 4) * 512 + lane * 8;
        bf16x8 a0 = *(const bf16x8*)(pA0);
        bf16x8 a1 = *(const bf16x8*)(pA0 + 512);
        bf16x8 a2 = *(const bf16x8*)(pA0 + 1024);
        bf16x8 a3 = *(const bf16x8*)(pA0 + 1536);
        g00 = __builtin_amdgcn_mfma_f32_16x16x32_bf16(a0, gg0, g00, 0, 0, 0);
        g01 = __builtin_amdgcn_mfma_f32_16x16x32_bf16(a0, gg1, g01, 0, 0, 0);
        g10 = __builtin_amdgcn_mfma_f32_16x16x32_bf16(a1, gg0, g10, 0, 0, 0);
        g11 = __builtin_amdgcn_mfma_f32_16x16x32_bf16(a1, gg1, g11, 0, 0, 0);
        g20 = __builtin_amdgcn_mfma_f32_16x16x32_bf16(a2, gg0, g20, 0, 0, 0);
        g21 = __builtin_amdgcn_mfma_f32_16x16x32_bf16(a2, gg1, g21, 0, 0, 0);
        g30 = __builtin_amdgcn_mfma_f32_16x16x32_bf16(a3, gg0, g30, 0, 0, 0);
        g31 = __builtin_amdgcn_mfma_f32_16x16x32_bf16(a3, gg1, g31, 0, 0, 0);
      }
      __builtin_amdgcn_s_setprio(0);
    }

    // ---- dump partials into OWN slice, reduce, update C (registers) ----
    {
      float* dmp = (float*)pool + wid * (SLICE / 2);
      *(f32x4*)(dmp +    0 + lane * 4) = g00;
      *(f32x4*)(dmp +  256 + lane * 4) = g01;
      *(f32x4*)(dmp +  512 + lane * 4) = g10;
      *(f32x4*)(dmp +  768 + lane * 4) = g11;
      *(f32x4*)(dmp + 1024 + lane * 4) = g20;
      *(f32x4*)(dmp + 1280 + lane * 4) = g21;
      *(f32x4*)(dmp + 1536 + lane * 4) = g30;
      *(f32x4*)(dmp + 1792 + lane * 4) = g31;
    }
    __syncthreads();
    {
      const float* poolF = (const float*)pool;
      f32x4 tot0 = {0.f, 0.f, 0.f, 0.f};
      f32x4 tot1 = {0.f, 0.f, 0.f, 0.f};
      #pragma unroll
      for (int v = 0; v < 4; ++v) {
        tot0 += *(const f32x4*)(poolF + v * (SLICE / 2) + (wid * 2 + 0) * 256 + lane * 4);
        tot1 += *(const f32x4*)(poolF + v * (SLICE / 2) + (wid * 2 + 1) * 256 + lane * 4);
      }
      Creg0 -= LR * tot0;
      Creg1 -= LR * tot1;
      if (c < 12 && it < 2) {
        #pragma unroll
        for (int r = 0; r < 4; ++r) {
          int k = kr + r;
          Cbf[(k >> 5) * 512 + (((k >> 3) & 3) * 16 + c) * 8 + (k & 7)] = f2h(Creg0[r]);
          Cbf[1024 + (k >> 5) * 512 + (((k >> 3) & 3) * 16 + c) * 8 + (k & 7)] = f2h(Creg1[r]);
        }
      }
    }
    __syncthreads();
  }

  // ---- stage final C -> pool fp32 [s][k][m], then coalesced out ----
  {
    float* poolF = (float*)pool;
    if (c < 12) {
      #pragma unroll
      for (int r = 0; r < 4; ++r) {
        int k = kr + r;
        poolF[sl * OutStr + k * 3 + fm]       = Creg0[r];
        poolF[(sl + 4) * OutStr + k * 3 + fm] = Creg1[r];
      }
    }
  }
  __syncthreads();
  {
    const float* poolF = (const float*)pool;
    #pragma unroll
    for (int sg2 = 0; sg2 < 2; ++sg2) {
      const int ps = wid + sg2 * 4;
      float* op = out + ((size_t)(bg + ps) * KK + lane) * 3;
      op[0] = poolF[ps * OutStr + lane * 3 + 0];
      op[1] = poolF[ps * OutStr + lane * 3 + 1];
      op[2] = poolF[ps * OutStr + lane * 3 + 2];
    }
  }
}

extern "C" void kernel_launch(void* const* d_in, const int* in_sizes, int n_in,
                              void* d_out, int out_size, void* d_ws, size_t ws_size,
                              hipStream_t stream) {
  const float* R_U     = (const float*)d_in[0];
  const float* alpha   = (const float*)d_in[1];
  const float* beta    = (const float*)d_in[2];
  const float* lambdas = (const float*)d_in[3];
  const float* B       = (const float*)d_in[4];
  const float* Bd      = (const float*)d_in[5];
  const float* Bdd     = (const float*)d_in[6];
  const float* Bddd    = (const float*)d_in[7];
  const float* Bp      = (const float*)d_in[8];
  unsigned short* ws = (unsigned short*)d_ws;
  const int nB = in_sizes[1];   // 16384

  hipLaunchKernelGGL(prep_kernel, dim3(640), dim3(256), 0, stream,
                     B, Bd, Bdd, Bddd, Bp, ws);
  hipLaunchKernelGGL(copt_kernel, dim3(nB / SS), dim3(256), 0, stream,
                     R_U, alpha, beta, lambdas, ws, (float*)d_out);
}